// Round 9
// baseline (238.246 us; speedup 1.0000x reference)
//
#include <hip/hip_runtime.h>
#include <cstdint>
#include <cstddef>

// Problem constants
#define BB  4
#define QQ  2048
#define SK  2048   // key length
#define DD  512
#define HH  8
#define DHH 64

typedef __bf16 bf16;
typedef bf16  bf16x8 __attribute__((ext_vector_type(8)));
typedef bf16  bf16x4 __attribute__((ext_vector_type(4)));
typedef float f32x4  __attribute__((ext_vector_type(4)));
typedef uint32_t u32x4 __attribute__((ext_vector_type(4)));

// ---- async global->LDS 16B copy (wave-uniform base + lane*16 semantics) ----
__device__ __forceinline__ void async16(void* lds, const void* g) {
  __builtin_amdgcn_global_load_lds(
      (const __attribute__((address_space(1))) unsigned int*)g,
      (__attribute__((address_space(3))) unsigned int*)lds, 16, 0, 0);
}

// pack two positive f32 into one u32 of 2 bf16 (truncation) via v_perm_b32
__device__ __forceinline__ uint32_t pk2(float lo, float hi) {
  return __builtin_amdgcn_perm(__builtin_bit_cast(uint32_t, hi),
                               __builtin_bit_cast(uint32_t, lo), 0x07060302u);
}

// ---- weights-only f32 -> bf16 (2 MB out; activations convert in-GEMM) ----
__global__ __launch_bounds__(256) void cvt_w(
    const float* __restrict__ w0, const float* __restrict__ w1,
    const float* __restrict__ w2, const float* __restrict__ w3,
    bf16* __restrict__ d0, bf16* __restrict__ d1, bf16* __restrict__ d2,
    bf16* __restrict__ d3, int nw4) {
  int i = blockIdx.x * 256 + threadIdx.x;
  const float* s;
  bf16* d;
  if (i < nw4)             { s = w0; d = d0; }
  else if (i < 2 * nw4)    { s = w1; d = d1; i -= nw4; }
  else if (i < 3 * nw4)    { s = w2; d = d2; i -= 2 * nw4; }
  else if (i < 4 * nw4)    { s = w3; d = d3; i -= 3 * nw4; }
  else return;
  float4 vv = ((const float4*)s)[i];
  bf16x4 o;
  o[0] = (bf16)vv.x; o[1] = (bf16)vv.y; o[2] = (bf16)vv.z; o[3] = (bf16)vv.w;
  ((bf16x4*)d)[i] = o;
}

// ---- Pipelined 64x64 GEMM: D[m][n] = sum_k A[m][k]*B[n][k], K=512 ----
// Port of the attention kernel's PROVEN loop (7/7 deterministic rounds):
// triple-buffered async16 W staging + ONE raw s_barrier + counted vmcnt
// per iter. ZERO ds_writes (round-6's race lived in the mixed
// ds_write+lgkmcnt path): X operand goes global -> reg ping-pong ->
// in-register RNE convert -> MFMA fragments, never touching LDS.
// Per iter: issue stageW(it+1) [2 async16/wave] + loadX(it+1)
// [8 float4 or 4 dwordx4/wave] -> vmcnt(BS) retires batch(it), leaves
// batch(it+1) in flight ACROSS the barrier -> s_barrier -> compute(it).
// Buffer safety = attn's proof verbatim: stage(it+1) writes buf[(it+1)%3],
// whose last readers (compute(it-2)) finished before barrier(it-1), which
// this wave passed before issuing. Full unroll keeps all reg-array
// indices static (rule #20). Batch instruction counts are exact: async16
// is one op, float4/bf16x8 loads are dwordx4 (not mergeable), memory
// clobbers pin batch boundaries -> vmcnt counts provable.
// XSIDE: 1 = X is B operand (swapped GEMMs), 0 = X is A (V proj).
// XF32:  X is f32 (convert in-register, bit-identical to a cvt pass).
template <int XSIDE, bool XF32, typename XT, typename EpiF>
__device__ __forceinline__ void gemm64p(
    bf16* __restrict__ lW3, const bf16* __restrict__ W,
    const XT* __restrict__ X, int tW, int tX, EpiF epi_fn) {
  const int tid  = threadIdx.x;
  const int l    = tid & 63;
  const int w    = tid >> 6;
  const int lrow = l & 15, lq = l >> 4, rx = lrow & 7;
  const int wm = (w >> 1) * 32, wn = (w & 1) * 32;
  const int wW = XSIDE ? wm : wn;        // W-side wave base (m or n)
  const int wX = XSIDE ? wn : wm;        // X-side wave base
  constexpr int BS = XF32 ? 10 : 6;      // vmem ops per batch per wave

  float4 rg[2][8];                       // f32 X ping-pong (XF32)
  bf16x8 xbr[2][4];                      // bf16 X ping-pong (!XF32)

  auto stageW = [&](int it) {
    bf16* dst = lW3 + (it % 3) * 4096;
    const int kt = it * 64;
#pragma unroll
    for (int j = 0; j < 2; ++j) {
      int c = j * 256 + tid, row = c >> 3, gcc = (c & 7) ^ (row & 7);
      async16(&dst[c * 8], &W[(size_t)(tW + row) * DD + kt + gcc * 8]);
    }
  };
  auto loadX = [&](int it) {
    const int kt = it * 64, pp = it & 1;
#pragma unroll
    for (int ks = 0; ks < 2; ++ks)
#pragma unroll
      for (int t = 0; t < 2; ++t) {
        const XT* p = &X[(size_t)(tX + wX + t * 16 + lrow) * DD
                         + kt + ks * 32 + lq * 8];
        if constexpr (XF32) {
          rg[pp][(ks * 2 + t) * 2]     = *(const float4*)p;
          rg[pp][(ks * 2 + t) * 2 + 1] = *(const float4*)(p + 4);
        } else {
          xbr[pp][ks * 2 + t] = *(const bf16x8*)p;
        }
      }
  };

  f32x4 acc[2][2] = {};
  stageW(0);
  loadX(0);
#pragma unroll
  for (int it = 0; it < 8; ++it) {
    if (it + 1 < 8) {
      stageW(it + 1);
      loadX(it + 1);
      asm volatile("s_waitcnt vmcnt(%0)" :: "i"(BS) : "memory");
    } else {
      asm volatile("s_waitcnt vmcnt(0)" ::: "memory");
    }
    __builtin_amdgcn_s_barrier();        // raw: batch(it+1) stays in flight
    asm volatile("" ::: "memory");       // fence LDS reads below barrier

    const bf16* buf = lW3 + (it % 3) * 4096;
    const int pp = it & 1;
    bf16x8 xf[2][2];                     // [ks][t]
#pragma unroll
    for (int ks = 0; ks < 2; ++ks)
#pragma unroll
      for (int t = 0; t < 2; ++t) {
        if constexpr (XF32) {
          float4 a = rg[pp][(ks * 2 + t) * 2];
          float4 b = rg[pp][(ks * 2 + t) * 2 + 1];
          bf16x8 o;
          o[0] = (bf16)a.x; o[1] = (bf16)a.y; o[2] = (bf16)a.z; o[3] = (bf16)a.w;
          o[4] = (bf16)b.x; o[5] = (bf16)b.y; o[6] = (bf16)b.z; o[7] = (bf16)b.w;
          xf[ks][t] = o;
        } else {
          xf[ks][t] = xbr[pp][ks * 2 + t];
        }
      }
#pragma unroll
    for (int ks = 0; ks < 2; ++ks) {
      bf16x8 wf[2];
#pragma unroll
      for (int t = 0; t < 2; ++t) {
        int row = wW + t * 16 + lrow;
        wf[t] = *(const bf16x8*)&buf[(row * 8 + ((ks * 4 + lq) ^ rx)) * 8];
      }
#pragma unroll
      for (int mt = 0; mt < 2; ++mt)
#pragma unroll
        for (int nt = 0; nt < 2; ++nt)
          acc[mt][nt] = __builtin_amdgcn_mfma_f32_16x16x32_bf16(
              XSIDE ? wf[mt] : xf[ks][mt], XSIDE ? xf[ks][nt] : wf[nt],
              acc[mt][nt], 0, 0, 0);
    }
  }

  const int tA = XSIDE ? tW : tX, tB = XSIDE ? tX : tW;
#pragma unroll
  for (int mt = 0; mt < 2; ++mt)
#pragma unroll
    for (int nt = 0; nt < 2; ++nt)
      epi_fn(acc[mt][nt], tA + wm + mt * 16 + lq * 4, tB + wn + nt * 16 + lrow);
}

// fused Q/K/V projections, blockIdx.y selects. 64x64 tiles: grid (1024,3).
// tW = (x>>7)*64 (8 out-dim tiles), tX = (x&127)*64 (128 token tiles):
// blocks sharing one X panel differ by 128 in blockIdx.x (same mod 8 ->
// same XCD -> panel fetched once per XCD). Activations f32 direct to regs.
// z<2 (Q,K): SWAPPED, W=A (out-dim), X=B (tokens).
// z==2 (V): normal, X=A (tokens), W=B (out-dim).
__global__ __launch_bounds__(256, 4) void proj3(
    const float* __restrict__ xq, const bf16* __restrict__ wq, bf16* __restrict__ qh,
    const float* __restrict__ xk, const bf16* __restrict__ wk, bf16* __restrict__ kh,
    const float* __restrict__ xv, const bf16* __restrict__ wv, bf16* __restrict__ vt,
    float qscale) {
  __shared__ __align__(16) bf16 lW3[3 * 64 * 64];   // 24 KB triple-buffer
  const int z = blockIdx.y, x = blockIdx.x;
  const int tW = (x >> 7) * 64, tX = (x & 127) * 64;
  if (z < 2) {
    const bf16*  W = z == 0 ? wq : wk;
    const float* Xf = z == 0 ? xq : xk;
    bf16* Cout     = z == 0 ? qh : kh;
    const float scale = z == 0 ? qscale : 1.0f;
    gemm64p<1, true>(lW3, W, Xf, tW, tX,
                     [&](const f32x4& a, int row0, int col) {
      int b2 = col >> 11, s = col & 2047;      // token
      int h2 = row0 >> 6, dh0 = row0 & 63;     // out-dim (4 consecutive dh)
      bf16x4 o;
#pragma unroll
      for (int r = 0; r < 4; ++r) o[r] = (bf16)(a[r] * scale);
      *(bf16x4*)&Cout[((size_t)(b2 * HH + h2) * QQ + s) * DHH + dh0] = o;
    });
  } else {
    gemm64p<0, true>(lW3, wv, xv, tW, tX,
                     [&](const f32x4& a, int row0, int col) {
      int b2 = row0 >> 11, s0 = row0 & 2047;   // 4 consecutive keys
      int h2 = col >> 6,  dh = col & 63;
      int tile = s0 >> 6, kk = s0 & 63;
      int g = kk >> 4, a2 = (kk >> 2) & 3;
      int idx0 = ((g >> 1) * 4 + a2) * 8 + (g & 1) * 4;   // PV permutation
      bf16x4 o;
#pragma unroll
      for (int r = 0; r < 4; ++r) o[r] = (bf16)a[r];
      *(bf16x4*)&vt[((size_t)(b2 * HH + h2) * DHH + dh) * SK + tile * 64 + idx0] = o;
    });
  }
}

// output projection, SWAPPED: A=wo (m=out-col, LDS triple-buffer), B=ao
// (n=token, bf16 frags direct to regs). Same pipelined structure and XCD
// grouping (x = p + 128*m). float4 stores to d_out [token][512].
__global__ __launch_bounds__(256, 4) void proj_o(
    const bf16* __restrict__ wo, const bf16* __restrict__ ao,
    float* __restrict__ Cout) {
  __shared__ __align__(16) bf16 lW3[3 * 64 * 64];   // 24 KB triple-buffer
  const int x = blockIdx.x;
  const int tW = (x >> 7) * 64, tX = (x & 127) * 64;
  gemm64p<1, false, bf16>(lW3, wo, ao, tW, tX,
                          [&](const f32x4& a, int row0, int col) {
    *(float4*)&Cout[(size_t)col * DD + row0] = *(const float4*)&a;
  });
}

// ---- Attention, SINGLE-PASS: S^T = K·Q^T, no-max softmax ----
// UNCHANGED (passing since round 3). grid (bh=32, qt=16); block = 128
// queries (32/wave); full valid-KV walk per block; normalize in registers,
// write bf16 ao directly. Triple-buffered LDS, ONE raw s_barrier +
// counted vmcnt(4) per tile (T3/T4); T5 setprio.
__global__ __launch_bounds__(256, 3) void attn_fused(
    const bf16* __restrict__ qh, const bf16* __restrict__ kh,
    const bf16* __restrict__ vt, const int* __restrict__ valid_lens,
    bf16* __restrict__ ao) {
  __shared__ __align__(16) bf16 lK[3][64 * 64];   // [key][dh], swizzled
  __shared__ __align__(16) bf16 lV[3][64 * 64];   // [dh][key-permuted], swizzled
  const int tid  = threadIdx.x;
  const int l    = tid & 63;
  const int w    = tid >> 6;
  const int lrow = l & 15, lq = l >> 4;
  const int rx   = lrow & 7;
  const int bh = blockIdx.x;
  const int b = bh >> 3, h = bh & 7;
  const int qt = blockIdx.y;
  const int vl  = valid_lens[b];
  const int nkt = (vl + 63) >> 6;        // >= 1 (vl >= 1)

  const int q0 = qt * 128 + w * 32;
  const bf16* qbase = qh + (size_t)bh * QQ * DHH;
  const bf16* kbase = kh + (size_t)bh * SK * DHH;
  const bf16* vbase = vt + (size_t)bh * DHH * SK;

  auto stageKV = [&](int k0, int buf) {
#pragma unroll
    for (int j = 0; j < 2; ++j) {
      int c = j * 256 + tid, row = c >> 3, gcc = (c & 7) ^ (row & 7);
      async16(&lK[buf][c * 8], &kbase[(size_t)(k0 + row) * DHH + gcc * 8]);
    }
#pragma unroll
    for (int j = 0; j < 2; ++j) {
      int c = j * 256 + tid, row = c >> 3, gcc = (c & 7) ^ (row & 7);
      async16(&lV[buf][c * 8], &vbase[(size_t)row * SK + k0 + gcc * 8]);
    }
  };

  // Q fragments (B-operand: n=lane&15=query, k=quad*8+j), 2 query groups
  bf16x8 qf[2][2];
#pragma unroll
  for (int g = 0; g < 2; ++g)
#pragma unroll
    for (int ks = 0; ks < 2; ++ks)
      qf[g][ks] = *(const bf16x8*)
          &qbase[(size_t)(q0 + g * 16 + lrow) * DHH + ks * 32 + lq * 8];

  f32x4 acc[2][4] = {};                  // O^T[dh=mt*16+lq*4+r][q group g]
  float rs[2] = {0.f, 0.f};

  stageKV(0, 0);
  // Drain prologue (Q loads + first stage). After this, the only
  // outstanding VMEM ops inside the loop are stage() ops -> counted waits.
  asm volatile("s_waitcnt vmcnt(0)" ::: "memory");

  for (int kt = 0; kt < nkt; ++kt) {
    const int bi = kt % 3;
    if (kt + 1 < nkt) {                  // block-uniform branch
      stageKV((kt + 1) * 64, (kt + 1) % 3);
      // wait only for stage(kt): 4 ops of stage(kt+1) may stay in flight
      asm volatile("s_waitcnt vmcnt(4)" ::: "memory");
    } else {
      asm volatile("s_waitcnt vmcnt(0)" ::: "memory");
    }
    __builtin_amdgcn_s_barrier();        // raw: no compiler vmcnt(0) drain
    asm volatile("" ::: "memory");       // fence LDS reads below barrier
    const bf16* bufK = lK[bi];
    const bf16* bufV = lV[bi];
    const int k0 = kt * 64;

    // S^T = K · Q^T (A = K rows; kf shared across both query groups)
    f32x4 s[2][4] = {};
    __builtin_amdgcn_s_setprio(1);
#pragma unroll
    for (int ks = 0; ks < 2; ++ks) {
#pragma unroll
      for (int t = 0; t < 4; ++t) {
        int row = t * 16 + lrow;
        int chunkc = row * 8 + ((ks * 4 + lq) ^ rx);
        bf16x8 kf = *(const bf16x8*)&bufK[chunkc * 8];
#pragma unroll
        for (int g = 0; g < 2; ++g)
          s[g][t] = __builtin_amdgcn_mfma_f32_16x16x32_bf16(
              kf, qf[g][ks], s[g][t], 0, 0, 0);
      }
    }
    __builtin_amdgcn_s_setprio(0);

    if (vl < k0 + 64) {                  // partial tile only: mask
#pragma unroll
      for (int t = 0; t < 4; ++t) {
        int kb = k0 + t * 16 + lq * 4;
#pragma unroll
        for (int r = 0; r < 4; ++r)
          if (kb + r >= vl) { s[0][t][r] = -1e30f; s[1][t][r] = -1e30f; }
      }
    }

    // p = exp2(s) directly (|s| small; masked -> exactly 0)
#pragma unroll
    for (int g = 0; g < 2; ++g)
#pragma unroll
      for (int t = 0; t < 4; ++t)
#pragma unroll
        for (int r = 0; r < 4; ++r) {
          float p = __builtin_amdgcn_exp2f(s[g][t][r]);
          rs[g] += p;
          s[g][t][r] = p;
        }

    // O^T += V^T · P  (vt PV-ready; vf shared across query groups)
#pragma unroll
    for (int p2 = 0; p2 < 2; ++p2) {
      u32x4 pu[2];
#pragma unroll
      for (int g = 0; g < 2; ++g) {
        pu[g][0] = pk2(s[g][2 * p2][0], s[g][2 * p2][1]);
        pu[g][1] = pk2(s[g][2 * p2][2], s[g][2 * p2][3]);
        pu[g][2] = pk2(s[g][2 * p2 + 1][0], s[g][2 * p2 + 1][1]);
        pu[g][3] = pk2(s[g][2 * p2 + 1][2], s[g][2 * p2 + 1][3]);
      }
      bf16x8 pb0 = __builtin_bit_cast(bf16x8, pu[0]);
      bf16x8 pb1 = __builtin_bit_cast(bf16x8, pu[1]);
      int cc = (p2 * 4 + lq) ^ rx;
      __builtin_amdgcn_s_setprio(1);
#pragma unroll
      for (int mt = 0; mt < 4; ++mt) {
        int row = mt * 16 + lrow;
        bf16x8 vf = *(const bf16x8*)&bufV[(row * 8 + cc) * 8];
        acc[0][mt] = __builtin_amdgcn_mfma_f32_16x16x32_bf16(
            vf, pb0, acc[0][mt], 0, 0, 0);
        acc[1][mt] = __builtin_amdgcn_mfma_f32_16x16x32_bf16(
            vf, pb1, acc[1][mt], 0, 0, 0);
      }
      __builtin_amdgcn_s_setprio(0);
    }
  }

  // full softmax denominator (sum over all lq quads of this query column)
#pragma unroll
  for (int g = 0; g < 2; ++g) {
    rs[g] += __shfl_xor(rs[g], 16);
    rs[g] += __shfl_xor(rs[g], 32);      // every lane now has full sum
  }

  // normalize + write bf16 ao[token][h*64+dh] directly
#pragma unroll
  for (int g = 0; g < 2; ++g) {
    float inv = 1.0f / rs[g];
    int q = q0 + g * 16 + lrow;
#pragma unroll
    for (int mt = 0; mt < 4; ++mt) {
      bf16x4 o;
#pragma unroll
      for (int r = 0; r < 4; ++r) o[r] = (bf16)(acc[g][mt][r] * inv);
      *(bf16x4*)&ao[((size_t)(b * QQ + q)) * DD + h * DHH + mt * 16 + lq * 4] = o;
    }
  }
}

extern "C" void kernel_launch(void* const* d_in, const int* in_sizes, int n_in,
                              void* d_out, int out_size, void* d_ws, size_t ws_size,
                              hipStream_t stream) {
  const float* queries    = (const float*)d_in[0];
  const float* keys       = (const float*)d_in[1];
  const float* values     = (const float*)d_in[2];
  const int*   valid_lens = (const int*)d_in[3];
  const float* W_q = (const float*)d_in[4];
  const float* W_k = (const float*)d_in[5];
  const float* W_v = (const float*)d_in[6];
  const float* W_o = (const float*)d_in[7];

  const size_t NX = (size_t)BB * QQ * DD;   // 4194304
  const size_t NW = (size_t)DD * DD;        // 262144

  bf16* wq = (bf16*)d_ws;       // bf16 weights
  bf16* wk = wq + NW;
  bf16* wv = wk + NW;
  bf16* wo = wv + NW;
  bf16* qh = wo + NW;           // [B,H,S,DH] (pre-scaled by 1/8*log2e)
  bf16* kh = qh + NX;           // [B,H,S,DH]
  bf16* vt = kh + NX;           // [B,H,DH,S] PV-ready key order
  bf16* ao = vt + NX;           // attention output [token][512] bf16

  dim3 blk(256);
  const int nw4 = (int)(NW / 4);
  cvt_w<<<dim3((4 * nw4 + 255) / 256), blk, 0, stream>>>(
      W_q, W_k, W_v, W_o, wq, wk, wv, wo, nw4);

  const float qscale = 0.125f * 1.44269504088896340736f;  // 1/sqrt(64)*log2e
  proj3<<<dim3(1024, 3), blk, 0, stream>>>(queries, wq, qh, keys, wk, kh,
                                           values, wv, vt, qscale);

  attn_fused<<<dim3(BB * HH, QQ / 128), blk, 0, stream>>>(
      qh, kh, vt, valid_lens, ao);

  proj_o<<<dim3(1024), blk, 0, stream>>>(wo, ao, (float*)d_out);
}

// Round 10
// 177.067 us; speedup vs baseline: 1.3455x; 1.3455x over previous
//
#include <hip/hip_runtime.h>
#include <cstdint>
#include <cstddef>

// Problem constants
#define BB  4
#define QQ  2048
#define SK  2048   // key length
#define DD  512
#define HH  8
#define DHH 64

typedef __bf16 bf16;
typedef bf16  bf16x8 __attribute__((ext_vector_type(8)));
typedef bf16  bf16x4 __attribute__((ext_vector_type(4)));
typedef float f32x4  __attribute__((ext_vector_type(4)));
typedef uint32_t u32x4 __attribute__((ext_vector_type(4)));

// ---- async global->LDS 16B copy (wave-uniform base + lane*16 semantics) ----
__device__ __forceinline__ void async16(void* lds, const void* g) {
  __builtin_amdgcn_global_load_lds(
      (const __attribute__((address_space(1))) unsigned int*)g,
      (__attribute__((address_space(3))) unsigned int*)lds, 16, 0, 0);
}

// pack two positive f32 into one u32 of 2 bf16 (truncation) via v_perm_b32
__device__ __forceinline__ uint32_t pk2(float lo, float hi) {
  return __builtin_amdgcn_perm(__builtin_bit_cast(uint32_t, hi),
                               __builtin_bit_cast(uint32_t, lo), 0x07060302u);
}

// ---- weights-only f32 -> bf16 (2 MB out; activations convert in-GEMM) ----
__global__ __launch_bounds__(256) void cvt_w(
    const float* __restrict__ w0, const float* __restrict__ w1,
    const float* __restrict__ w2, const float* __restrict__ w3,
    bf16* __restrict__ d0, bf16* __restrict__ d1, bf16* __restrict__ d2,
    bf16* __restrict__ d3, int nw4) {
  int i = blockIdx.x * 256 + threadIdx.x;
  const float* s;
  bf16* d;
  if (i < nw4)             { s = w0; d = d0; }
  else if (i < 2 * nw4)    { s = w1; d = d1; i -= nw4; }
  else if (i < 3 * nw4)    { s = w2; d = d2; i -= 2 * nw4; }
  else if (i < 4 * nw4)    { s = w3; d = d3; i -= 3 * nw4; }
  else return;
  float4 vv = ((const float4*)s)[i];
  bf16x4 o;
  o[0] = (bf16)vv.x; o[1] = (bf16)vv.y; o[2] = (bf16)vv.z; o[3] = (bf16)vv.w;
  ((bf16x4*)d)[i] = o;
}

// ---- 64x64-tile GEMM, BK=128 (4 K-iters), issue-early staging ----
// Round-8 (proven deterministic, 44us) cost = 8 drains x exposed latency:
// stage was issued immediately before its own __syncthreads drain. Fixes:
// (1) BK=128 -> 4 drains (same k-visit order -> bit-identical numerics);
// (2) W double-buffered, stageW(t+1)+loadXraw(t+1) issued right AFTER the
//     publish-sync so they overlap all of compute(t); the next sync's
//     vmcnt(0) drain finds them mostly retired.
// Ordering uses ONLY __syncthreads() (rounds 5/7/8-proven family; the
// round-6 race lived in raw-barrier mechanics). X path = f32 -> reg ->
// RNE convert -> ds_write (round-5/8 proven), block-staged (FETCH dedup).
// Swizzle at 16 chunks/row: global chunk g = (c&8)|((c^row)&7); reader
// slot for k-chunk K at row r: (K&8)|((K^r)&7)  (low-3-bit XOR only).
// XSIDE: 1 = X is B operand (Q/K proj, swapped), 0 = X is A (V proj).
template <int XSIDE, typename EpiF>
__device__ __forceinline__ void gemm64b(
    bf16* __restrict__ lW2, bf16* __restrict__ lX,
    const bf16* __restrict__ W, const float* __restrict__ X,
    int tW, int tX, EpiF epi_fn) {
  const int tid  = threadIdx.x;
  const int l    = tid & 63;
  const int w    = tid >> 6;
  const int lrow = l & 15, lq = l >> 4, rx = lrow & 7;
  const int wm = (w >> 1) * 32, wn = (w & 1) * 32;
  const int wW = XSIDE ? wm : wn;        // W-side wave base (m or n)
  const int wX = XSIDE ? wn : wm;        // X-side wave base

  float4 rg[2][8];                       // f32 X ping-pong (static idx)
  auto loadXraw = [&](int it) {
    const int kt = it * 128, pp = it & 1;
#pragma unroll
    for (int j = 0; j < 4; ++j) {
      int c = j * 256 + tid, row = c >> 4, gcc = (c & 8) | ((c ^ row) & 7);
      const float* s = &X[(size_t)(tX + row) * DD + kt + gcc * 8];
      rg[pp][2 * j]     = *(const float4*)s;
      rg[pp][2 * j + 1] = *(const float4*)(s + 4);
    }
  };
  auto writeX = [&](int it) {
    const int pp = it & 1;
#pragma unroll
    for (int j = 0; j < 4; ++j) {
      int c = j * 256 + tid;
      float4 a = rg[pp][2 * j], b = rg[pp][2 * j + 1];
      bf16x8 o;
      o[0] = (bf16)a.x; o[1] = (bf16)a.y; o[2] = (bf16)a.z; o[3] = (bf16)a.w;
      o[4] = (bf16)b.x; o[5] = (bf16)b.y; o[6] = (bf16)b.z; o[7] = (bf16)b.w;
      *(bf16x8*)&lX[c * 8] = o;
    }
  };
  auto stageW = [&](int it) {
    bf16* dst = lW2 + (it & 1) * 8192;   // 64*128 elems per buffer
    const int kt = it * 128;
#pragma unroll
    for (int j = 0; j < 4; ++j) {
      int c = j * 256 + tid, row = c >> 4, gcc = (c & 8) | ((c ^ row) & 7);
      async16(&dst[c * 8], &W[(size_t)(tW + row) * DD + kt + gcc * 8]);
    }
  };

  f32x4 acc[2][2] = {};
  stageW(0);
  loadXraw(0);
#pragma unroll
  for (int it = 0; it < 4; ++it) {
    __syncthreads();   // drains stage(it)+loadX(it) (overlapped w/ compute(it-1)
                       // for it>0); also: compute(it-1)'s lX readers done
    writeX(it);
    __syncthreads();   // publish lX (ds writes); nothing big in vmem queue
    if (it + 1 < 4) {  // issue-early: overlaps ALL of compute(it)
      stageW(it + 1);
      loadXraw(it + 1);
    }
    const bf16* bufW = lW2 + (it & 1) * 8192;
#pragma unroll
    for (int ks = 0; ks < 4; ++ks) {
      const int ksl  = ks * 4 + lq;                  // k-chunk 0..15
      const int slot = (ksl & 8) | ((ksl ^ rx) & 7); // swizzled LDS slot
      bf16x8 wf[2], xfr[2];
#pragma unroll
      for (int t = 0; t < 2; ++t) {
        int rW = wW + t * 16 + lrow, rX = wX + t * 16 + lrow;
        wf[t]  = *(const bf16x8*)&bufW[(rW * 16 + slot) * 8];
        xfr[t] = *(const bf16x8*)&lX [(rX * 16 + slot) * 8];
      }
#pragma unroll
      for (int mt = 0; mt < 2; ++mt)
#pragma unroll
        for (int nt = 0; nt < 2; ++nt)
          acc[mt][nt] = __builtin_amdgcn_mfma_f32_16x16x32_bf16(
              XSIDE ? wf[mt] : xfr[mt], XSIDE ? xfr[nt] : wf[nt],
              acc[mt][nt], 0, 0, 0);
    }
  }

  const int tA = XSIDE ? tW : tX, tB = XSIDE ? tX : tW;
#pragma unroll
  for (int mt = 0; mt < 2; ++mt)
#pragma unroll
    for (int nt = 0; nt < 2; ++nt)
      epi_fn(acc[mt][nt], tA + wm + mt * 16 + lq * 4, tB + wn + nt * 16 + lrow);
}

// fused Q/K/V projections, blockIdx.y selects. 64x64 tiles: grid (1024,3).
// tW = (x>>7)*64 (8 out-dim tiles), tX = (x&127)*64 (128 token tiles):
// blocks sharing one X panel differ by 128 in blockIdx.x (same mod 8 ->
// same XCD -> panel fetched once per XCD). Activations f32 direct.
// LDS = 32KB W-dbuf + 16KB X = 48KB -> 3 blocks/CU.
// z<2 (Q,K): SWAPPED, W=A (out-dim), X=B (tokens).
// z==2 (V): normal, X=A (tokens), W=B (out-dim).
__global__ __launch_bounds__(256, 3) void proj3(
    const float* __restrict__ xq, const bf16* __restrict__ wq, bf16* __restrict__ qh,
    const float* __restrict__ xk, const bf16* __restrict__ wk, bf16* __restrict__ kh,
    const float* __restrict__ xv, const bf16* __restrict__ wv, bf16* __restrict__ vt,
    float qscale) {
  __shared__ __align__(16) bf16 smem[2 * 64 * 128 + 64 * 128];   // 48 KB
  bf16* lW2 = smem;
  bf16* lX  = smem + 2 * 64 * 128;
  const int z = blockIdx.y, x = blockIdx.x;
  const int tW = (x >> 7) * 64, tX = (x & 127) * 64;
  if (z < 2) {
    const bf16*  W = z == 0 ? wq : wk;
    const float* Xf = z == 0 ? xq : xk;
    bf16* Cout     = z == 0 ? qh : kh;
    const float scale = z == 0 ? qscale : 1.0f;
    gemm64b<1>(lW2, lX, W, Xf, tW, tX,
               [&](const f32x4& a, int row0, int col) {
      int b2 = col >> 11, s = col & 2047;      // token
      int h2 = row0 >> 6, dh0 = row0 & 63;     // out-dim (4 consecutive dh)
      bf16x4 o;
#pragma unroll
      for (int r = 0; r < 4; ++r) o[r] = (bf16)(a[r] * scale);
      *(bf16x4*)&Cout[((size_t)(b2 * HH + h2) * QQ + s) * DHH + dh0] = o;
    });
  } else {
    gemm64b<0>(lW2, lX, wv, xv, tW, tX,
               [&](const f32x4& a, int row0, int col) {
      int b2 = row0 >> 11, s0 = row0 & 2047;   // 4 consecutive keys
      int h2 = col >> 6,  dh = col & 63;
      int tile = s0 >> 6, kk = s0 & 63;
      int g = kk >> 4, a2 = (kk >> 2) & 3;
      int idx0 = ((g >> 1) * 4 + a2) * 8 + (g & 1) * 4;   // PV permutation
      bf16x4 o;
#pragma unroll
      for (int r = 0; r < 4; ++r) o[r] = (bf16)a[r];
      *(bf16x4*)&vt[((size_t)(b2 * HH + h2) * DHH + dh) * SK + tile * 64 + idx0] = o;
    });
  }
}

// output projection, SWAPPED: A=wo (out-col), B=ao (token), both bf16 via
// async16, BOTH double-buffered, BK=128, ONE sync/iter with issue-early
// staging (drain overlapped with compute). 64 KB LDS -> 2 blocks/CU.
// Same XCD grouping (x = p + 128*m). float4 stores to d_out [token][512].
__global__ __launch_bounds__(256, 2) void proj_o(
    const bf16* __restrict__ wo, const bf16* __restrict__ ao,
    float* __restrict__ Cout) {
  __shared__ __align__(16) bf16 lW2[2 * 64 * 128];   // 32 KB
  __shared__ __align__(16) bf16 lX2[2 * 64 * 128];   // 32 KB
  const int x = blockIdx.x;
  const int tW = (x >> 7) * 64, tX = (x & 127) * 64;
  const int tid  = threadIdx.x;
  const int l    = tid & 63;
  const int w    = tid >> 6;
  const int lrow = l & 15, lq = l >> 4, rx = lrow & 7;
  const int wm = (w >> 1) * 32, wn = (w & 1) * 32;

  auto stage = [&](const bf16* src, int trow, bf16* dst, int it) {
    const int kt = it * 128;
#pragma unroll
    for (int j = 0; j < 4; ++j) {
      int c = j * 256 + tid, row = c >> 4, gcc = (c & 8) | ((c ^ row) & 7);
      async16(&dst[c * 8], &src[(size_t)(trow + row) * DD + kt + gcc * 8]);
    }
  };

  f32x4 acc[2][2] = {};
  stage(wo, tW, lW2, 0);
  stage(ao, tX, lX2, 0);
#pragma unroll
  for (int it = 0; it < 4; ++it) {
    __syncthreads();   // drains stage(it) (overlapped w/ compute(it-1) for it>0)
    if (it + 1 < 4) {  // issue-early: overlaps compute(it)
      stage(wo, tW, lW2 + ((it + 1) & 1) * 8192, it + 1);
      stage(ao, tX, lX2 + ((it + 1) & 1) * 8192, it + 1);
    }
    const bf16* bufW = lW2 + (it & 1) * 8192;
    const bf16* bufX = lX2 + (it & 1) * 8192;
#pragma unroll
    for (int ks = 0; ks < 4; ++ks) {
      const int ksl  = ks * 4 + lq;
      const int slot = (ksl & 8) | ((ksl ^ rx) & 7);
      bf16x8 wf[2], xfr[2];
#pragma unroll
      for (int t = 0; t < 2; ++t) {
        int rW = wm + t * 16 + lrow, rX = wn + t * 16 + lrow;
        wf[t]  = *(const bf16x8*)&bufW[(rW * 16 + slot) * 8];
        xfr[t] = *(const bf16x8*)&bufX[(rX * 16 + slot) * 8];
      }
#pragma unroll
      for (int mt = 0; mt < 2; ++mt)
#pragma unroll
        for (int nt = 0; nt < 2; ++nt)
          acc[mt][nt] = __builtin_amdgcn_mfma_f32_16x16x32_bf16(
              wf[mt], xfr[nt], acc[mt][nt], 0, 0, 0);
    }
  }

#pragma unroll
  for (int mt = 0; mt < 2; ++mt)
#pragma unroll
    for (int nt = 0; nt < 2; ++nt) {
      int row0 = tW + wm + mt * 16 + lq * 4;
      int col  = tX + wn + nt * 16 + lrow;
      *(float4*)&Cout[(size_t)col * DD + row0] = *(const float4*)&acc[mt][nt];
    }
}

// ---- Attention, SINGLE-PASS: S^T = K·Q^T, no-max softmax ----
// UNCHANGED (passing since round 3). grid (bh=32, qt=16); block = 128
// queries (32/wave); full valid-KV walk per block; normalize in registers,
// write bf16 ao directly. Triple-buffered LDS, ONE raw s_barrier +
// counted vmcnt(4) per tile (T3/T4); T5 setprio.
__global__ __launch_bounds__(256, 3) void attn_fused(
    const bf16* __restrict__ qh, const bf16* __restrict__ kh,
    const bf16* __restrict__ vt, const int* __restrict__ valid_lens,
    bf16* __restrict__ ao) {
  __shared__ __align__(16) bf16 lK[3][64 * 64];   // [key][dh], swizzled
  __shared__ __align__(16) bf16 lV[3][64 * 64];   // [dh][key-permuted], swizzled
  const int tid  = threadIdx.x;
  const int l    = tid & 63;
  const int w    = tid >> 6;
  const int lrow = l & 15, lq = l >> 4;
  const int rx   = lrow & 7;
  const int bh = blockIdx.x;
  const int b = bh >> 3, h = bh & 7;
  const int qt = blockIdx.y;
  const int vl  = valid_lens[b];
  const int nkt = (vl + 63) >> 6;        // >= 1 (vl >= 1)

  const int q0 = qt * 128 + w * 32;
  const bf16* qbase = qh + (size_t)bh * QQ * DHH;
  const bf16* kbase = kh + (size_t)bh * SK * DHH;
  const bf16* vbase = vt + (size_t)bh * DHH * SK;

  auto stageKV = [&](int k0, int buf) {
#pragma unroll
    for (int j = 0; j < 2; ++j) {
      int c = j * 256 + tid, row = c >> 3, gcc = (c & 7) ^ (row & 7);
      async16(&lK[buf][c * 8], &kbase[(size_t)(k0 + row) * DHH + gcc * 8]);
    }
#pragma unroll
    for (int j = 0; j < 2; ++j) {
      int c = j * 256 + tid, row = c >> 3, gcc = (c & 7) ^ (row & 7);
      async16(&lV[buf][c * 8], &vbase[(size_t)row * SK + k0 + gcc * 8]);
    }
  };

  // Q fragments (B-operand: n=lane&15=query, k=quad*8+j), 2 query groups
  bf16x8 qf[2][2];
#pragma unroll
  for (int g = 0; g < 2; ++g)
#pragma unroll
    for (int ks = 0; ks < 2; ++ks)
      qf[g][ks] = *(const bf16x8*)
          &qbase[(size_t)(q0 + g * 16 + lrow) * DHH + ks * 32 + lq * 8];

  f32x4 acc[2][4] = {};                  // O^T[dh=mt*16+lq*4+r][q group g]
  float rs[2] = {0.f, 0.f};

  stageKV(0, 0);
  // Drain prologue (Q loads + first stage). After this, the only
  // outstanding VMEM ops inside the loop are stage() ops -> counted waits.
  asm volatile("s_waitcnt vmcnt(0)" ::: "memory");

  for (int kt = 0; kt < nkt; ++kt) {
    const int bi = kt % 3;
    if (kt + 1 < nkt) {                  // block-uniform branch
      stageKV((kt + 1) * 64, (kt + 1) % 3);
      // wait only for stage(kt): 4 ops of stage(kt+1) may stay in flight
      asm volatile("s_waitcnt vmcnt(4)" ::: "memory");
    } else {
      asm volatile("s_waitcnt vmcnt(0)" ::: "memory");
    }
    __builtin_amdgcn_s_barrier();        // raw: no compiler vmcnt(0) drain
    asm volatile("" ::: "memory");       // fence LDS reads below barrier
    const bf16* bufK = lK[bi];
    const bf16* bufV = lV[bi];
    const int k0 = kt * 64;

    // S^T = K · Q^T (A = K rows; kf shared across both query groups)
    f32x4 s[2][4] = {};
    __builtin_amdgcn_s_setprio(1);
#pragma unroll
    for (int ks = 0; ks < 2; ++ks) {
#pragma unroll
      for (int t = 0; t < 4; ++t) {
        int row = t * 16 + lrow;
        int chunkc = row * 8 + ((ks * 4 + lq) ^ rx);
        bf16x8 kf = *(const bf16x8*)&bufK[chunkc * 8];
#pragma unroll
        for (int g = 0; g < 2; ++g)
          s[g][t] = __builtin_amdgcn_mfma_f32_16x16x32_bf16(
              kf, qf[g][ks], s[g][t], 0, 0, 0);
      }
    }
    __builtin_amdgcn_s_setprio(0);

    if (vl < k0 + 64) {                  // partial tile only: mask
#pragma unroll
      for (int t = 0; t < 4; ++t) {
        int kb = k0 + t * 16 + lq * 4;
#pragma unroll
        for (int r = 0; r < 4; ++r)
          if (kb + r >= vl) { s[0][t][r] = -1e30f; s[1][t][r] = -1e30f; }
      }
    }

    // p = exp2(s) directly (|s| small; masked -> exactly 0)
#pragma unroll
    for (int g = 0; g < 2; ++g)
#pragma unroll
      for (int t = 0; t < 4; ++t)
#pragma unroll
        for (int r = 0; r < 4; ++r) {
          float p = __builtin_amdgcn_exp2f(s[g][t][r]);
          rs[g] += p;
          s[g][t][r] = p;
        }

    // O^T += V^T · P  (vt PV-ready; vf shared across query groups)
#pragma unroll
    for (int p2 = 0; p2 < 2; ++p2) {
      u32x4 pu[2];
#pragma unroll
      for (int g = 0; g < 2; ++g) {
        pu[g][0] = pk2(s[g][2 * p2][0], s[g][2 * p2][1]);
        pu[g][1] = pk2(s[g][2 * p2][2], s[g][2 * p2][3]);
        pu[g][2] = pk2(s[g][2 * p2 + 1][0], s[g][2 * p2 + 1][1]);
        pu[g][3] = pk2(s[g][2 * p2 + 1][2], s[g][2 * p2 + 1][3]);
      }
      bf16x8 pb0 = __builtin_bit_cast(bf16x8, pu[0]);
      bf16x8 pb1 = __builtin_bit_cast(bf16x8, pu[1]);
      int cc = (p2 * 4 + lq) ^ rx;
      __builtin_amdgcn_s_setprio(1);
#pragma unroll
      for (int mt = 0; mt < 4; ++mt) {
        int row = mt * 16 + lrow;
        bf16x8 vf = *(const bf16x8*)&bufV[(row * 8 + cc) * 8];
        acc[0][mt] = __builtin_amdgcn_mfma_f32_16x16x32_bf16(
            vf, pb0, acc[0][mt], 0, 0, 0);
        acc[1][mt] = __builtin_amdgcn_mfma_f32_16x16x32_bf16(
            vf, pb1, acc[1][mt], 0, 0, 0);
      }
      __builtin_amdgcn_s_setprio(0);
    }
  }

  // full softmax denominator (sum over all lq quads of this query column)
#pragma unroll
  for (int g = 0; g < 2; ++g) {
    rs[g] += __shfl_xor(rs[g], 16);
    rs[g] += __shfl_xor(rs[g], 32);      // every lane now has full sum
  }

  // normalize + write bf16 ao[token][h*64+dh] directly
#pragma unroll
  for (int g = 0; g < 2; ++g) {
    float inv = 1.0f / rs[g];
    int q = q0 + g * 16 + lrow;
#pragma unroll
    for (int mt = 0; mt < 4; ++mt) {
      bf16x4 o;
#pragma unroll
      for (int r = 0; r < 4; ++r) o[r] = (bf16)(acc[g][mt][r] * inv);
      *(bf16x4*)&ao[((size_t)(b * QQ + q)) * DD + h * DHH + mt * 16 + lq * 4] = o;
    }
  }
}

extern "C" void kernel_launch(void* const* d_in, const int* in_sizes, int n_in,
                              void* d_out, int out_size, void* d_ws, size_t ws_size,
                              hipStream_t stream) {
  const float* queries    = (const float*)d_in[0];
  const float* keys       = (const float*)d_in[1];
  const float* values     = (const float*)d_in[2];
  const int*   valid_lens = (const int*)d_in[3];
  const float* W_q = (const float*)d_in[4];
  const float* W_k = (const float*)d_in[5];
  const float* W_v = (const float*)d_in[6];
  const float* W_o = (const float*)d_in[7];

  const size_t NX = (size_t)BB * QQ * DD;   // 4194304
  const size_t NW = (size_t)DD * DD;        // 262144

  bf16* wq = (bf16*)d_ws;       // bf16 weights
  bf16* wk = wq + NW;
  bf16* wv = wk + NW;
  bf16* wo = wv + NW;
  bf16* qh = wo + NW;           // [B,H,S,DH] (pre-scaled by 1/8*log2e)
  bf16* kh = qh + NX;           // [B,H,S,DH]
  bf16* vt = kh + NX;           // [B,H,DH,S] PV-ready key order
  bf16* ao = vt + NX;           // attention output [token][512] bf16

  dim3 blk(256);
  const int nw4 = (int)(NW / 4);
  cvt_w<<<dim3((4 * nw4 + 255) / 256), blk, 0, stream>>>(
      W_q, W_k, W_v, W_o, wq, wk, wv, wo, nw4);

  const float qscale = 0.125f * 1.44269504088896340736f;  // 1/sqrt(64)*log2e
  proj3<<<dim3(1024, 3), blk, 0, stream>>>(queries, wq, qh, keys, wk, kh,
                                           values, wv, vt, qscale);

  attn_fused<<<dim3(BB * HH, QQ / 128), blk, 0, stream>>>(
      qh, kh, vt, valid_lens, ao);

  proj_o<<<dim3(1024), blk, 0, stream>>>(wo, ao, (float*)d_out);
}

// Round 11
// 176.461 us; speedup vs baseline: 1.3501x; 1.0034x over previous
//
#include <hip/hip_runtime.h>
#include <cstdint>
#include <cstddef>

// Problem constants
#define BB  4
#define QQ  2048
#define SK  2048   // key length
#define DD  512
#define HH  8
#define DHH 64

typedef __bf16 bf16;
typedef bf16  bf16x8 __attribute__((ext_vector_type(8)));
typedef bf16  bf16x4 __attribute__((ext_vector_type(4)));
typedef float f32x4  __attribute__((ext_vector_type(4)));
typedef uint32_t u32x4 __attribute__((ext_vector_type(4)));

// ---- async global->LDS 16B copy (wave-uniform base + lane*16 semantics) ----
__device__ __forceinline__ void async16(void* lds, const void* g) {
  __builtin_amdgcn_global_load_lds(
      (const __attribute__((address_space(1))) unsigned int*)g,
      (__attribute__((address_space(3))) unsigned int*)lds, 16, 0, 0);
}

// pack two positive f32 into one u32 of 2 bf16 (truncation) via v_perm_b32
__device__ __forceinline__ uint32_t pk2(float lo, float hi) {
  return __builtin_amdgcn_perm(__builtin_bit_cast(uint32_t, hi),
                               __builtin_bit_cast(uint32_t, lo), 0x07060302u);
}

// ---- weights-only f32 -> bf16 (2 MB out; activations convert in-GEMM) ----
__global__ __launch_bounds__(256) void cvt_w(
    const float* __restrict__ w0, const float* __restrict__ w1,
    const float* __restrict__ w2, const float* __restrict__ w3,
    bf16* __restrict__ d0, bf16* __restrict__ d1, bf16* __restrict__ d2,
    bf16* __restrict__ d3, int nw4) {
  int i = blockIdx.x * 256 + threadIdx.x;
  const float* s;
  bf16* d;
  if (i < nw4)             { s = w0; d = d0; }
  else if (i < 2 * nw4)    { s = w1; d = d1; i -= nw4; }
  else if (i < 3 * nw4)    { s = w2; d = d2; i -= 2 * nw4; }
  else if (i < 4 * nw4)    { s = w3; d = d3; i -= 3 * nw4; }
  else return;
  float4 vv = ((const float4*)s)[i];
  bf16x4 o;
  o[0] = (bf16)vv.x; o[1] = (bf16)vv.y; o[2] = (bf16)vv.z; o[3] = (bf16)vv.w;
  ((bf16x4*)d)[i] = o;
}

// ---- 64x64-tile GEMM, BK=128, issue-early staging, FIXED LDS layout ----
// Round-10's 16-chunk/row swizzle caused 3.1M LDS bank conflicts (the
// sub-tile-half bit sat uniformly at addr bit 7; round-8's 8-chunk/row
// layout put lrow's low bit there and measured ZERO conflicts). Fix: each
// 64x128 buffer = TWO 64x64 sub-tiles, each in the bit-exact round-8
// layout. Staging map (c = j*256+tid, j=0..3):
//   kh = c>>9, cc = c&511, row = cc>>3, gcc = (cc&7)^(row&7)
//   global k-elem = kt + kh*64 + gcc*8 ; LDS dest = c*8 (linear, async16-ok)
// Reader (k-chunk ksl = ks*4+lq, 0..15):
//   chunk = (ksl>>3)*512 + row*8 + ((ksl&7)^rx)
// -> per-instruction bank pattern identical to round 8 (measured 0).
// Pipeline (proven deterministic in round 10): per iter
//   sync1 (drains stage(it)+loadX(it), overlapped w/ compute(it-1))
//   -> writeX(it) -> sync2 (publish ds) -> issue stage/loadX(it+1)
//   -> compute(it).  Only __syncthreads(); W double-buffered.
// Same k-visit order as rounds 5-10 -> bit-identical numerics.
// XSIDE: 1 = X is B operand (Q/K proj, swapped), 0 = X is A (V proj).
template <int XSIDE, typename EpiF>
__device__ __forceinline__ void gemm64c(
    bf16* __restrict__ lW2, bf16* __restrict__ lX,
    const bf16* __restrict__ W, const float* __restrict__ X,
    int tW, int tX, EpiF epi_fn) {
  const int tid  = threadIdx.x;
  const int l    = tid & 63;
  const int w    = tid >> 6;
  const int lrow = l & 15, lq = l >> 4, rx = lrow & 7;
  const int wm = (w >> 1) * 32, wn = (w & 1) * 32;
  const int wW = XSIDE ? wm : wn;        // W-side wave base (m or n)
  const int wX = XSIDE ? wn : wm;        // X-side wave base

  float4 rg[2][8];                       // f32 X ping-pong (static idx)
  auto loadXraw = [&](int it) {
    const int kt = it * 128, pp = it & 1;
#pragma unroll
    for (int j = 0; j < 4; ++j) {
      int c = j * 256 + tid, cc = c & 511, kh = c >> 9;
      int row = cc >> 3, gcc = (cc & 7) ^ (row & 7);
      const float* s = &X[(size_t)(tX + row) * DD + kt + kh * 64 + gcc * 8];
      rg[pp][2 * j]     = *(const float4*)s;
      rg[pp][2 * j + 1] = *(const float4*)(s + 4);
    }
  };
  auto writeX = [&](int it) {
    const int pp = it & 1;
#pragma unroll
    for (int j = 0; j < 4; ++j) {
      int c = j * 256 + tid;
      float4 a = rg[pp][2 * j], b = rg[pp][2 * j + 1];
      bf16x8 o;
      o[0] = (bf16)a.x; o[1] = (bf16)a.y; o[2] = (bf16)a.z; o[3] = (bf16)a.w;
      o[4] = (bf16)b.x; o[5] = (bf16)b.y; o[6] = (bf16)b.z; o[7] = (bf16)b.w;
      *(bf16x8*)&lX[c * 8] = o;
    }
  };
  auto stageW = [&](int it) {
    bf16* dst = lW2 + (it & 1) * 8192;   // 64*128 elems per buffer
    const int kt = it * 128;
#pragma unroll
    for (int j = 0; j < 4; ++j) {
      int c = j * 256 + tid, cc = c & 511, kh = c >> 9;
      int row = cc >> 3, gcc = (cc & 7) ^ (row & 7);
      async16(&dst[c * 8], &W[(size_t)(tW + row) * DD + kt + kh * 64 + gcc * 8]);
    }
  };

  f32x4 acc[2][2] = {};
  stageW(0);
  loadXraw(0);
#pragma unroll
  for (int it = 0; it < 4; ++it) {
    __syncthreads();   // drains stage(it)+loadX(it) (overlapped w/ compute(it-1)
                       // for it>0); also: compute(it-1)'s lX readers done
    writeX(it);
    __syncthreads();   // publish lX ds_writes (vmem queue empty here)
    if (it + 1 < 4) {  // issue-early: overlaps ALL of compute(it)
      stageW(it + 1);
      loadXraw(it + 1);
    }
    const bf16* bufW = lW2 + (it & 1) * 8192;
#pragma unroll
    for (int ks = 0; ks < 4; ++ks) {
      const int ksl  = ks * 4 + lq;                  // k-chunk 0..15
      const int base = (ksl >> 3) * 512;             // sub-tile
      const int slot = (ksl & 7) ^ rx;               // round-8 swizzle
      bf16x8 wf[2], xfr[2];
#pragma unroll
      for (int t = 0; t < 2; ++t) {
        int rW = wW + t * 16 + lrow, rX = wX + t * 16 + lrow;
        wf[t]  = *(const bf16x8*)&bufW[(base + rW * 8 + slot) * 8];
        xfr[t] = *(const bf16x8*)&lX [(base + rX * 8 + slot) * 8];
      }
#pragma unroll
      for (int mt = 0; mt < 2; ++mt)
#pragma unroll
        for (int nt = 0; nt < 2; ++nt)
          acc[mt][nt] = __builtin_amdgcn_mfma_f32_16x16x32_bf16(
              XSIDE ? wf[mt] : xfr[mt], XSIDE ? xfr[nt] : wf[nt],
              acc[mt][nt], 0, 0, 0);
    }
  }

  const int tA = XSIDE ? tW : tX, tB = XSIDE ? tX : tW;
#pragma unroll
  for (int mt = 0; mt < 2; ++mt)
#pragma unroll
    for (int nt = 0; nt < 2; ++nt)
      epi_fn(acc[mt][nt], tA + wm + mt * 16 + lq * 4, tB + wn + nt * 16 + lrow);
}

// fused Q/K/V projections, blockIdx.y selects. 64x64 tiles: grid (1024,3).
// tW = (x>>7)*64 (8 out-dim tiles), tX = (x&127)*64 (128 token tiles):
// blocks sharing one X panel differ by 128 in blockIdx.x (same mod 8 ->
// same XCD -> panel fetched once per XCD). Activations f32 direct.
// LDS = 32KB W-dbuf + 16KB X = 48KB -> 3 blocks/CU.
// z<2 (Q,K): SWAPPED, W=A (out-dim), X=B (tokens).
// z==2 (V): normal, X=A (tokens), W=B (out-dim).
__global__ __launch_bounds__(256, 3) void proj3(
    const float* __restrict__ xq, const bf16* __restrict__ wq, bf16* __restrict__ qh,
    const float* __restrict__ xk, const bf16* __restrict__ wk, bf16* __restrict__ kh,
    const float* __restrict__ xv, const bf16* __restrict__ wv, bf16* __restrict__ vt,
    float qscale) {
  __shared__ __align__(16) bf16 smem[2 * 64 * 128 + 64 * 128];   // 48 KB
  bf16* lW2 = smem;
  bf16* lX  = smem + 2 * 64 * 128;
  const int z = blockIdx.y, x = blockIdx.x;
  const int tW = (x >> 7) * 64, tX = (x & 127) * 64;
  if (z < 2) {
    const bf16*  W = z == 0 ? wq : wk;
    const float* Xf = z == 0 ? xq : xk;
    bf16* Cout     = z == 0 ? qh : kh;
    const float scale = z == 0 ? qscale : 1.0f;
    gemm64c<1>(lW2, lX, W, Xf, tW, tX,
               [&](const f32x4& a, int row0, int col) {
      int b2 = col >> 11, s = col & 2047;      // token
      int h2 = row0 >> 6, dh0 = row0 & 63;     // out-dim (4 consecutive dh)
      bf16x4 o;
#pragma unroll
      for (int r = 0; r < 4; ++r) o[r] = (bf16)(a[r] * scale);
      *(bf16x4*)&Cout[((size_t)(b2 * HH + h2) * QQ + s) * DHH + dh0] = o;
    });
  } else {
    gemm64c<0>(lW2, lX, wv, xv, tW, tX,
               [&](const f32x4& a, int row0, int col) {
      int b2 = row0 >> 11, s0 = row0 & 2047;   // 4 consecutive keys
      int h2 = col >> 6,  dh = col & 63;
      int tile = s0 >> 6, kk = s0 & 63;
      int g = kk >> 4, a2 = (kk >> 2) & 3;
      int idx0 = ((g >> 1) * 4 + a2) * 8 + (g & 1) * 4;   // PV permutation
      bf16x4 o;
#pragma unroll
      for (int r = 0; r < 4; ++r) o[r] = (bf16)a[r];
      *(bf16x4*)&vt[((size_t)(b2 * HH + h2) * DHH + dh) * SK + tile * 64 + idx0] = o;
    });
  }
}

// output projection, SWAPPED: A=wo (out-col), B=ao (token), both bf16 via
// async16, BOTH double-buffered, BK=128, ONE sync/iter with issue-early
// staging. Same two-sub-tile round-8 LDS layout (fixes round-10's bank
// conflicts here too). 64 KB LDS -> 2 blocks/CU. XCD grouping x = p+128*m.
__global__ __launch_bounds__(256, 2) void proj_o(
    const bf16* __restrict__ wo, const bf16* __restrict__ ao,
    float* __restrict__ Cout) {
  __shared__ __align__(16) bf16 lW2[2 * 64 * 128];   // 32 KB
  __shared__ __align__(16) bf16 lX2[2 * 64 * 128];   // 32 KB
  const int x = blockIdx.x;
  const int tW = (x >> 7) * 64, tX = (x & 127) * 64;
  const int tid  = threadIdx.x;
  const int l    = tid & 63;
  const int w    = tid >> 6;
  const int lrow = l & 15, lq = l >> 4, rx = lrow & 7;
  const int wm = (w >> 1) * 32, wn = (w & 1) * 32;

  auto stage = [&](const bf16* src, int trow, bf16* dst, int it) {
    const int kt = it * 128;
#pragma unroll
    for (int j = 0; j < 4; ++j) {
      int c = j * 256 + tid, cc = c & 511, kh2 = c >> 9;
      int row = cc >> 3, gcc = (cc & 7) ^ (row & 7);
      async16(&dst[c * 8],
              &src[(size_t)(trow + row) * DD + kt + kh2 * 64 + gcc * 8]);
    }
  };

  f32x4 acc[2][2] = {};
  stage(wo, tW, lW2, 0);
  stage(ao, tX, lX2, 0);
#pragma unroll
  for (int it = 0; it < 4; ++it) {
    __syncthreads();   // drains stage(it) (overlapped w/ compute(it-1) for it>0)
    if (it + 1 < 4) {  // issue-early: overlaps compute(it)
      stage(wo, tW, lW2 + ((it + 1) & 1) * 8192, it + 1);
      stage(ao, tX, lX2 + ((it + 1) & 1) * 8192, it + 1);
    }
    const bf16* bufW = lW2 + (it & 1) * 8192;
    const bf16* bufX = lX2 + (it & 1) * 8192;
#pragma unroll
    for (int ks = 0; ks < 4; ++ks) {
      const int ksl  = ks * 4 + lq;
      const int base = (ksl >> 3) * 512;
      const int slot = (ksl & 7) ^ rx;
      bf16x8 wf[2], xfr[2];
#pragma unroll
      for (int t = 0; t < 2; ++t) {
        int rW = wm + t * 16 + lrow, rX = wn + t * 16 + lrow;
        wf[t]  = *(const bf16x8*)&bufW[(base + rW * 8 + slot) * 8];
        xfr[t] = *(const bf16x8*)&bufX[(base + rX * 8 + slot) * 8];
      }
#pragma unroll
      for (int mt = 0; mt < 2; ++mt)
#pragma unroll
        for (int nt = 0; nt < 2; ++nt)
          acc[mt][nt] = __builtin_amdgcn_mfma_f32_16x16x32_bf16(
              wf[mt], xfr[nt], acc[mt][nt], 0, 0, 0);
    }
  }

#pragma unroll
  for (int mt = 0; mt < 2; ++mt)
#pragma unroll
    for (int nt = 0; nt < 2; ++nt) {
      int row0 = tW + wm + mt * 16 + lq * 4;
      int col  = tX + wn + nt * 16 + lrow;
      *(float4*)&Cout[(size_t)col * DD + row0] = *(const float4*)&acc[mt][nt];
    }
}

// ---- Attention, SINGLE-PASS: S^T = K·Q^T, no-max softmax ----
// UNCHANGED (passing since round 3). grid (bh=32, qt=16); block = 128
// queries (32/wave); full valid-KV walk per block; normalize in registers,
// write bf16 ao directly. Triple-buffered LDS, ONE raw s_barrier +
// counted vmcnt(4) per tile (T3/T4); T5 setprio.
__global__ __launch_bounds__(256, 3) void attn_fused(
    const bf16* __restrict__ qh, const bf16* __restrict__ kh,
    const bf16* __restrict__ vt, const int* __restrict__ valid_lens,
    bf16* __restrict__ ao) {
  __shared__ __align__(16) bf16 lK[3][64 * 64];   // [key][dh], swizzled
  __shared__ __align__(16) bf16 lV[3][64 * 64];   // [dh][key-permuted], swizzled
  const int tid  = threadIdx.x;
  const int l    = tid & 63;
  const int w    = tid >> 6;
  const int lrow = l & 15, lq = l >> 4;
  const int rx   = lrow & 7;
  const int bh = blockIdx.x;
  const int b = bh >> 3, h = bh & 7;
  const int qt = blockIdx.y;
  const int vl  = valid_lens[b];
  const int nkt = (vl + 63) >> 6;        // >= 1 (vl >= 1)

  const int q0 = qt * 128 + w * 32;
  const bf16* qbase = qh + (size_t)bh * QQ * DHH;
  const bf16* kbase = kh + (size_t)bh * SK * DHH;
  const bf16* vbase = vt + (size_t)bh * DHH * SK;

  auto stageKV = [&](int k0, int buf) {
#pragma unroll
    for (int j = 0; j < 2; ++j) {
      int c = j * 256 + tid, row = c >> 3, gcc = (c & 7) ^ (row & 7);
      async16(&lK[buf][c * 8], &kbase[(size_t)(k0 + row) * DHH + gcc * 8]);
    }
#pragma unroll
    for (int j = 0; j < 2; ++j) {
      int c = j * 256 + tid, row = c >> 3, gcc = (c & 7) ^ (row & 7);
      async16(&lV[buf][c * 8], &vbase[(size_t)row * SK + k0 + gcc * 8]);
    }
  };

  // Q fragments (B-operand: n=lane&15=query, k=quad*8+j), 2 query groups
  bf16x8 qf[2][2];
#pragma unroll
  for (int g = 0; g < 2; ++g)
#pragma unroll
    for (int ks = 0; ks < 2; ++ks)
      qf[g][ks] = *(const bf16x8*)
          &qbase[(size_t)(q0 + g * 16 + lrow) * DHH + ks * 32 + lq * 8];

  f32x4 acc[2][4] = {};                  // O^T[dh=mt*16+lq*4+r][q group g]
  float rs[2] = {0.f, 0.f};

  stageKV(0, 0);
  // Drain prologue (Q loads + first stage). After this, the only
  // outstanding VMEM ops inside the loop are stage() ops -> counted waits.
  asm volatile("s_waitcnt vmcnt(0)" ::: "memory");

  for (int kt = 0; kt < nkt; ++kt) {
    const int bi = kt % 3;
    if (kt + 1 < nkt) {                  // block-uniform branch
      stageKV((kt + 1) * 64, (kt + 1) % 3);
      // wait only for stage(kt): 4 ops of stage(kt+1) may stay in flight
      asm volatile("s_waitcnt vmcnt(4)" ::: "memory");
    } else {
      asm volatile("s_waitcnt vmcnt(0)" ::: "memory");
    }
    __builtin_amdgcn_s_barrier();        // raw: no compiler vmcnt(0) drain
    asm volatile("" ::: "memory");       // fence LDS reads below barrier
    const bf16* bufK = lK[bi];
    const bf16* bufV = lV[bi];
    const int k0 = kt * 64;

    // S^T = K · Q^T (A = K rows; kf shared across both query groups)
    f32x4 s[2][4] = {};
    __builtin_amdgcn_s_setprio(1);
#pragma unroll
    for (int ks = 0; ks < 2; ++ks) {
#pragma unroll
      for (int t = 0; t < 4; ++t) {
        int row = t * 16 + lrow;
        int chunkc = row * 8 + ((ks * 4 + lq) ^ rx);
        bf16x8 kf = *(const bf16x8*)&bufK[chunkc * 8];
#pragma unroll
        for (int g = 0; g < 2; ++g)
          s[g][t] = __builtin_amdgcn_mfma_f32_16x16x32_bf16(
              kf, qf[g][ks], s[g][t], 0, 0, 0);
      }
    }
    __builtin_amdgcn_s_setprio(0);

    if (vl < k0 + 64) {                  // partial tile only: mask
#pragma unroll
      for (int t = 0; t < 4; ++t) {
        int kb = k0 + t * 16 + lq * 4;
#pragma unroll
        for (int r = 0; r < 4; ++r)
          if (kb + r >= vl) { s[0][t][r] = -1e30f; s[1][t][r] = -1e30f; }
      }
    }

    // p = exp2(s) directly (|s| small; masked -> exactly 0)
#pragma unroll
    for (int g = 0; g < 2; ++g)
#pragma unroll
      for (int t = 0; t < 4; ++t)
#pragma unroll
        for (int r = 0; r < 4; ++r) {
          float p = __builtin_amdgcn_exp2f(s[g][t][r]);
          rs[g] += p;
          s[g][t][r] = p;
        }

    // O^T += V^T · P  (vt PV-ready; vf shared across query groups)
#pragma unroll
    for (int p2 = 0; p2 < 2; ++p2) {
      u32x4 pu[2];
#pragma unroll
      for (int g = 0; g < 2; ++g) {
        pu[g][0] = pk2(s[g][2 * p2][0], s[g][2 * p2][1]);
        pu[g][1] = pk2(s[g][2 * p2][2], s[g][2 * p2][3]);
        pu[g][2] = pk2(s[g][2 * p2 + 1][0], s[g][2 * p2 + 1][1]);
        pu[g][3] = pk2(s[g][2 * p2 + 1][2], s[g][2 * p2 + 1][3]);
      }
      bf16x8 pb0 = __builtin_bit_cast(bf16x8, pu[0]);
      bf16x8 pb1 = __builtin_bit_cast(bf16x8, pu[1]);
      int cc = (p2 * 4 + lq) ^ rx;
      __builtin_amdgcn_s_setprio(1);
#pragma unroll
      for (int mt = 0; mt < 4; ++mt) {
        int row = mt * 16 + lrow;
        bf16x8 vf = *(const bf16x8*)&bufV[(row * 8 + cc) * 8];
        acc[0][mt] = __builtin_amdgcn_mfma_f32_16x16x32_bf16(
            vf, pb0, acc[0][mt], 0, 0, 0);
        acc[1][mt] = __builtin_amdgcn_mfma_f32_16x16x32_bf16(
            vf, pb1, acc[1][mt], 0, 0, 0);
      }
      __builtin_amdgcn_s_setprio(0);
    }
  }

  // full softmax denominator (sum over all lq quads of this query column)
#pragma unroll
  for (int g = 0; g < 2; ++g) {
    rs[g] += __shfl_xor(rs[g], 16);
    rs[g] += __shfl_xor(rs[g], 32);      // every lane now has full sum
  }

  // normalize + write bf16 ao[token][h*64+dh] directly
#pragma unroll
  for (int g = 0; g < 2; ++g) {
    float inv = 1.0f / rs[g];
    int q = q0 + g * 16 + lrow;
#pragma unroll
    for (int mt = 0; mt < 4; ++mt) {
      bf16x4 o;
#pragma unroll
      for (int r = 0; r < 4; ++r) o[r] = (bf16)(acc[g][mt][r] * inv);
      *(bf16x4*)&ao[((size_t)(b * QQ + q)) * DD + h * DHH + mt * 16 + lq * 4] = o;
    }
  }
}

extern "C" void kernel_launch(void* const* d_in, const int* in_sizes, int n_in,
                              void* d_out, int out_size, void* d_ws, size_t ws_size,
                              hipStream_t stream) {
  const float* queries    = (const float*)d_in[0];
  const float* keys       = (const float*)d_in[1];
  const float* values     = (const float*)d_in[2];
  const int*   valid_lens = (const int*)d_in[3];
  const float* W_q = (const float*)d_in[4];
  const float* W_k = (const float*)d_in[5];
  const float* W_v = (const float*)d_in[6];
  const float* W_o = (const float*)d_in[7];

  const size_t NX = (size_t)BB * QQ * DD;   // 4194304
  const size_t NW = (size_t)DD * DD;        // 262144

  bf16* wq = (bf16*)d_ws;       // bf16 weights
  bf16* wk = wq + NW;
  bf16* wv = wk + NW;
  bf16* wo = wv + NW;
  bf16* qh = wo + NW;           // [B,H,S,DH] (pre-scaled by 1/8*log2e)
  bf16* kh = qh + NX;           // [B,H,S,DH]
  bf16* vt = kh + NX;           // [B,H,DH,S] PV-ready key order
  bf16* ao = vt + NX;           // attention output [token][512] bf16

  dim3 blk(256);
  const int nw4 = (int)(NW / 4);
  cvt_w<<<dim3((4 * nw4 + 255) / 256), blk, 0, stream>>>(
      W_q, W_k, W_v, W_o, wq, wk, wv, wo, nw4);

  const float qscale = 0.125f * 1.44269504088896340736f;  // 1/sqrt(64)*log2e
  proj3<<<dim3(1024, 3), blk, 0, stream>>>(queries, wq, qh, keys, wk, kh,
                                           values, wv, vt, qscale);

  attn_fused<<<dim3(BB * HH, QQ / 128), blk, 0, stream>>>(
      qh, kh, vt, valid_lens, ao);

  proj_o<<<dim3(1024), blk, 0, stream>>>(wo, ao, (float*)d_out);
}